// Round 18
// baseline (366.998 us; speedup 1.0000x reference)
//
#include <hip/hip_runtime.h>
#include <hip/hip_bf16.h>

// Swin block, round 18 = round 17 + isolated no-max softmax.
//  - bmT pre-folds mask/pad to -1e30 -> exp underflows to exactly 0; real
//    scores |s| << 88 so exp(s) cannot overflow f32. P-store stays
//    NORMALIZED (e*inv) so no live-range growth (r11's regression came from
//    the deferred-inv live ranges + attn setprio, not the max removal).
//  - Removes 24 dependent 4-deep shfl-fmax chains + 72 fmax per block.
//  - Everything else identical to r17 (verified 362.3 us best).
//  - fallback: round-2 attn + round-7 mlp5 if ws too small.

using f32x4  = __attribute__((ext_vector_type(4))) float;
using short8 = __attribute__((ext_vector_type(8))) short;
typedef unsigned short ushort_t;

__device__ __forceinline__ ushort_t f2bf(float f) {
    __hip_bfloat16 h = __float2bfloat16(f);
    return __builtin_bit_cast(ushort_t, h);
}
__device__ __forceinline__ f32x4 mfma16(short8 a, short8 b, f32x4 c) {
    return __builtin_amdgcn_mfma_f32_16x16x32_bf16(a, b, c, 0, 0, 0);
}
// gelu(h) ~= h * sigmoid(1.5957691*h*(1+0.044715*h^2)); saturation-safe.
__device__ __forceinline__ float fast_gelu(float h) {
    float hh = h * h;
    float p  = __builtin_fmaf(hh, 0.044715f, 1.0f);
    float z  = h * (-1.5957691216057308f);
    float em = __expf(p * z);
    return h * __builtin_amdgcn_rcpf(1.0f + em);
}

#define CC 192

// ws offsets (bytes)
#define OFF_QKVT   0          // [576][192] bf16
#define OFF_PROJT  221184     // [192][192] bf16
#define OFF_FC1T   294912     // [768][192] bf16
#define OFF_FC2T   589824     // [192][768] bf16
#define OFF_BIAS   884736     // [6][49][49] f32
#define OFF_MASK   942592     // [64][49][49] f32
#define OFF_BMT    1557504    // [64][6][64][64] f32 (bias+mask, transposed, pad=-1e30)
#define OFF_QG     7848960    // [100352][192] bf16 (scaled Q)
#define OFF_KG     46384128   // [100352][192] bf16
#define OFF_VG     84919296   // [100352][192] bf16
#define WS_NEED    123454464
#define PREP_SMALL 610438
#define PREP_BIG   2183302

// ---------------- prep ----------------
__global__ void prep_kernel(const float* __restrict__ qkv_w, const float* __restrict__ proj_w,
                            const float* __restrict__ fc1_w, const float* __restrict__ fc2_w,
                            const float* __restrict__ rel_table,
                            ushort_t* __restrict__ qkvT, ushort_t* __restrict__ projT,
                            ushort_t* __restrict__ fc1T, ushort_t* __restrict__ fc2T,
                            float* __restrict__ biasT, float* __restrict__ maskT,
                            float* __restrict__ bmT, int full) {
    int idx = blockIdx.x * 256 + threadIdx.x;
    if (idx < 110592) { int n = idx / 192, k = idx % 192; qkvT[idx] = f2bf(qkv_w[k * 576 + n]); return; }
    idx -= 110592;
    if (idx < 36864) { int n = idx / 192, k = idx % 192; projT[idx] = f2bf(proj_w[k * 192 + n]); return; }
    idx -= 36864;
    if (idx < 147456) { int n = idx / 192, k = idx % 192; fc1T[idx] = f2bf(fc1_w[k * 768 + n]); return; }
    idx -= 147456;
    if (idx < 147456) { int n = idx / 768, k = idx % 768; fc2T[idx] = f2bf(fc2_w[k * 192 + n]); return; }
    idx -= 147456;
    if (idx < 14406) {
        int h = idx / 2401; int rest = idx % 2401; int a = rest / 49, b = rest % 49;
        int d = 13 * ((a % 7) - (b % 7) + (a / 7) - (b / 7) + 12);
        if (d > 168) d = 168;
        biasT[idx] = rel_table[d * 6 + h];
        return;
    }
    idx -= 14406;
    if (idx < 153664) {
        int w = idx / 2401; int rest = idx % 2401; int a = rest / 49, b = rest % 49;
        int wy = w / 8, wx = w % 8;
        int ya = wy * 7 + a / 7, xa = wx * 7 + a % 7;
        int yb = wy * 7 + b / 7, xb = wx * 7 + b % 7;
        int lya = ya < 49 ? 0 : (ya < 53 ? 1 : 2);
        int lxa = xa < 49 ? 0 : (xa < 53 ? 1 : 2);
        int lyb = yb < 49 ? 0 : (yb < 53 ? 1 : 2);
        int lxb = xb < 49 ? 0 : (xb < 53 ? 1 : 2);
        maskT[idx] = ((lya * 3 + lxa) != (lyb * 3 + lxb)) ? -100.0f : 0.0f;
        return;
    }
    idx -= 153664;
    if (full && idx < 1572864) {  // bmT[wi][h][col][row]
        int wi = idx / 24576; int r2 = idx % 24576;
        int h = r2 / 4096; int r3 = r2 % 4096;
        int col = r3 / 64, row = r3 % 64;
        float v = -1e30f;
        if (row < 49 && col < 49) {
            int d = 13 * ((row % 7) - (col % 7) + (row / 7) - (col / 7) + 12);
            if (d > 168) d = 168;
            float bias = rel_table[d * 6 + h];
            int wy = wi / 8, wx = wi % 8;
            int ya = wy * 7 + row / 7, xa = wx * 7 + row % 7;
            int yb = wy * 7 + col / 7, xb = wx * 7 + col % 7;
            int lya = ya < 49 ? 0 : (ya < 53 ? 1 : 2);
            int lxa = xa < 49 ? 0 : (xa < 53 ? 1 : 2);
            int lyb = yb < 49 ? 0 : (yb < 53 ? 1 : 2);
            int lxb = xb < 49 ? 0 : (xb < 53 ? 1 : 2);
            float mask = ((lya * 3 + lxa) != (lyb * 3 + lxb)) ? -100.0f : 0.0f;
            v = bias + mask;
        }
        bmT[idx] = v;
        return;
    }
}

// ---------------- phase A: LN1 + QKV GEMM, coalesced writes ----------------
__global__ __launch_bounds__(256, 3) void lnqkv_kernel(
    const float* __restrict__ x, const float* __restrict__ n1g, const float* __restrict__ n1b,
    const ushort_t* __restrict__ qkvT, const float* __restrict__ qkv_b,
    ushort_t* __restrict__ qg, ushort_t* __restrict__ kg, ushort_t* __restrict__ vg) {
    __shared__ ushort_t xln [64 * 200];
    __shared__ ushort_t qkvs[64 * 200];
    const int tid = threadIdx.x;
    const int wave = tid >> 6, lane = tid & 63;
    const int ln16 = lane & 15, sub = lane >> 4;
    const int t0 = blockIdx.x * 64;
    const f32x4 zero4 = {0.f, 0.f, 0.f, 0.f};

    {
        float g0 = n1g[lane], g1 = n1g[lane + 64], g2 = n1g[lane + 128];
        float bb0 = n1b[lane], bb1 = n1b[lane + 64], bb2 = n1b[lane + 128];
        for (int rb = 0; rb < 4; ++rb) {
            int row0 = wave * 16 + rb * 4;
            float v0[4], v1[4], v2[4], s[4], q[4];
            #pragma unroll
            for (int j = 0; j < 4; ++j) {
                const float* xr = x + (size_t)(t0 + row0 + j) * CC;
                v0[j] = xr[lane]; v1[j] = xr[lane + 64]; v2[j] = xr[lane + 128];
            }
            #pragma unroll
            for (int j = 0; j < 4; ++j) {
                s[j] = v0[j] + v1[j] + v2[j];
                q[j] = v0[j] * v0[j] + v1[j] * v1[j] + v2[j] * v2[j];
            }
            #pragma unroll
            for (int m = 32; m; m >>= 1) {
                #pragma unroll
                for (int j = 0; j < 4; ++j) { s[j] += __shfl_xor(s[j], m); q[j] += __shfl_xor(q[j], m); }
            }
            #pragma unroll
            for (int j = 0; j < 4; ++j) {
                float mu = s[j] * (1.0f / 192.0f);
                float var = q[j] * (1.0f / 192.0f) - mu * mu;
                float rs = rsqrtf(var + 1e-5f);
                int row = row0 + j;
                xln[row * 200 + lane]       = f2bf((v0[j] - mu) * rs * g0 + bb0);
                xln[row * 200 + lane + 64]  = f2bf((v1[j] - mu) * rs * g1 + bb1);
                xln[row * 200 + lane + 128] = f2bf((v2[j] - mu) * rs * g2 + bb2);
            }
        }
    }
    __syncthreads();

    ushort_t* dsts[3] = {qg, kg, vg};
    for (int v = 0; v < 3; ++v) {
        f32x4 acc[4][3];
        #pragma unroll
        for (int m = 0; m < 4; ++m)
            #pragma unroll
            for (int n = 0; n < 3; ++n) acc[m][n] = zero4;
        for (int kk = 0; kk < 6; ++kk) {
            short8 a[4];
            #pragma unroll
            for (int m = 0; m < 4; ++m)
                a[m] = *(const short8*)(xln + (m * 16 + ln16) * 200 + kk * 32 + 8 * sub);
            #pragma unroll
            for (int n = 0; n < 3; ++n) {
                short8 b = *(const short8*)(qkvT + (size_t)(v * 192 + (wave * 3 + n) * 16 + ln16) * 192 + kk * 32 + 8 * sub);
                #pragma unroll
                for (int m = 0; m < 4; ++m) acc[m][n] = mfma16(a[m], b, acc[m][n]);
            }
        }
        #pragma unroll
        for (int n = 0; n < 3; ++n) {
            int col = (wave * 3 + n) * 16 + ln16;
            float bv = qkv_b[v * 192 + col];
            #pragma unroll
            for (int m = 0; m < 4; ++m)
                #pragma unroll
                for (int r = 0; r < 4; ++r) {
                    int row = m * 16 + 4 * sub + r;
                    float val = acc[m][n][r] + bv;
                    if (v == 0) val *= 0.17677669529663689f;
                    qkvs[row * 200 + col] = f2bf(val);
                }
        }
        __syncthreads();
        ushort_t* dst = dsts[v];
        for (int i = tid; i < 1536; i += 256) {
            int row = i / 24, c = i % 24;
            short8 vv = *(const short8*)(qkvs + row * 200 + c * 8);
            *(short8*)(dst + (size_t)(t0 + row) * 192 + c * 8) = vv;
        }
        __syncthreads();
    }
}

// ---------------- phase B: FUSED attention + LN2 + MLP, v6-nomax ----------
// 1 block/window (2048), 4 waves, 38.4 KB LDS -> 4 blocks/CU.
__global__ __launch_bounds__(256, 4) void attnmlp_kernel(
    const float* __restrict__ x, const float* __restrict__ proj_b,
    const ushort_t* __restrict__ qg, const ushort_t* __restrict__ kg,
    const ushort_t* __restrict__ vg, const ushort_t* __restrict__ projT,
    const float* __restrict__ bmT,
    const float* __restrict__ n2g, const float* __restrict__ n2b,
    const float* __restrict__ fc1_b, const float* __restrict__ fc2_b,
    const ushort_t* __restrict__ fc1T, const ushort_t* __restrict__ fc2T,
    float* __restrict__ out) {
    __shared__ __align__(16) char smem[38416];
    ushort_t* vt   = (ushort_t*)smem;            // attn: [192][72]  (27,648)
    ushort_t* PO   = (ushort_t*)(smem + 27648);  // attn: [4][16*72] ( 9,216)
    ushort_t* aln  = (ushort_t*)smem;            // mlp:  [64][200]  (25,600)
    ushort_t* hidc = (ushort_t*)(smem + 25600);  // mlp:  [64][72]   ( 9,216)
    float*    fout = (float*)smem;               // stage:[49][196]  (38,416)

    const int tid = threadIdx.x;
    const int wave = tid >> 6, lane = tid & 63;
    const int ln16 = lane & 15, sub = lane >> 4;
    const int win = blockIdx.x;
    const int b = win >> 6, wi = win & 63;
    const int wy = wi >> 3, wx = wi & 7;
    const f32x4 zero4 = {0.f, 0.f, 0.f, 0.f};

    size_t tokA;
    {
        int j = wave * 16 + ln16; if (j > 48) j = 48;
        int y  = wy * 7 + j / 7 + 3; if (y >= 56) y -= 56;
        int xx = wx * 7 + j % 7 + 3; if (xx >= 56) xx -= 56;
        tokA = (size_t)(b * 3136 + y * 56 + xx);
    }
    size_t tokB[4];
    #pragma unroll
    for (int n = 0; n < 4; ++n) {
        int j = n * 16 + ln16; if (j > 48) j = 48;
        int y  = wy * 7 + j / 7 + 3; if (y >= 56) y -= 56;
        int xx = wx * 7 + j % 7 + 3; if (xx >= 56) xx -= 56;
        tokB[n] = (size_t)(b * 3136 + y * 56 + xx);
    }
    const float* bmw = bmT + (size_t)wi * 24576 + (size_t)(wave * 16 + 4 * sub);

    // ---- stage V^T for this window ----
    {
        int j = tid & 63;
        int jj = j < 49 ? j : 48;
        int y  = wy * 7 + jj / 7 + 3; if (y >= 56) y -= 56;
        int xx = wx * 7 + jj % 7 + 3; if (xx >= 56) xx -= 56;
        size_t tokV = (size_t)(b * 3136 + y * 56 + xx);
        const bool valid = j < 49;
        #pragma unroll
        for (int pass = 0; pass < 6; ++pass) {
            int c8 = pass * 32 + (tid >> 6) * 8;
            if (valid) {
                short8 vv = *(const short8*)(vg + tokV * 192 + c8);
                #pragma unroll
                for (int q = 0; q < 8; ++q) vt[(c8 + q) * 72 + j] = ((ushort_t*)&vv)[q];
            } else {
                #pragma unroll
                for (int q = 0; q < 8; ++q) vt[(c8 + q) * 72 + j] = 0;
            }
        }
    }

    f32x4 accP[12];
    #pragma unroll
    for (int n = 0; n < 12; ++n) accP[n] = zero4;
    ushort_t* Pw = PO + wave * (16 * 72);
    __syncthreads();  // vt ready

    for (int h = 0; h < 6; ++h) {
        // per-head loads (no cross-head pipeline; TLP hides latency)
        short8 qf = *(const short8*)(qg + tokA * 192 + h * 32 + 8 * sub);
        short8 kf[4];
        f32x4  bv[4];
        #pragma unroll
        for (int n = 0; n < 4; ++n) {
            kf[n] = *(const short8*)(kg + tokB[n] * 192 + h * 32 + 8 * sub);
            bv[n] = *(const f32x4*)(bmw + h * 4096 + (n * 16 + ln16) * 64);
        }
        f32x4 s4[4];
        #pragma unroll
        for (int n = 0; n < 4; ++n) s4[n] = mfma16(qf, kf[n], zero4);
        #pragma unroll
        for (int n = 0; n < 4; ++n)
            #pragma unroll
            for (int r = 0; r < 4; ++r) s4[n][r] += bv[n][r];
        // softmax without max pass: pad/mask pre-folded to -1e30 -> exp = 0
        // exactly; real |s| << 88 so exp(s) cannot overflow f32. P stored
        // NORMALIZED (no live-range growth vs r17).
        #pragma unroll
        for (int r = 0; r < 4; ++r) {
            float e0 = __expf(s4[0][r]), e1 = __expf(s4[1][r]);
            float e2 = __expf(s4[2][r]), e3 = __expf(s4[3][r]);
            float sm = e0 + e1 + e2 + e3;
            sm += __shfl_xor(sm, 1, 16);
            sm += __shfl_xor(sm, 2, 16);
            sm += __shfl_xor(sm, 4, 16);
            sm += __shfl_xor(sm, 8, 16);
            float inv = 1.0f / sm;
            int rl = 4 * sub + r;
            Pw[rl * 72 +      ln16] = f2bf(e0 * inv);
            Pw[rl * 72 + 16 + ln16] = f2bf(e1 * inv);
            Pw[rl * 72 + 32 + ln16] = f2bf(e2 * inv);
            Pw[rl * 72 + 48 + ln16] = f2bf(e3 * inv);
        }
        short8 ap0 = *(const short8*)(Pw + ln16 * 72 + 8 * sub);
        short8 ap1 = *(const short8*)(Pw + ln16 * 72 + 32 + 8 * sub);
        f32x4 o2[2]; o2[0] = zero4; o2[1] = zero4;
        #pragma unroll
        for (int n2 = 0; n2 < 2; ++n2) {
            short8 bv0 = *(const short8*)(vt + (h * 32 + n2 * 16 + ln16) * 72 + 8 * sub);
            short8 bv1 = *(const short8*)(vt + (h * 32 + n2 * 16 + ln16) * 72 + 32 + 8 * sub);
            o2[n2] = mfma16(ap0, bv0, o2[n2]);
            o2[n2] = mfma16(ap1, bv1, o2[n2]);
        }
        #pragma unroll
        for (int n2 = 0; n2 < 2; ++n2)
            #pragma unroll
            for (int r = 0; r < 4; ++r)
                Pw[(4 * sub + r) * 72 + n2 * 16 + ln16] = f2bf(o2[n2][r]);
        {
            short8 ao = *(const short8*)(Pw + ln16 * 72 + 8 * sub);
            #pragma unroll
            for (int n = 0; n < 12; ++n) {
                short8 bp = *(const short8*)(projT + (size_t)(n * 16 + ln16) * 192 + h * 32 + 8 * sub);
                accP[n] = mfma16(ao, bp, accP[n]);
            }
        }
    }

    // ---- epilogue A (coalesced): stage x into dead attn LDS, add resid,
    //      write v back to uniquely-owned slots, flush float4 to out ----
    __syncthreads();  // attn LDS (vt/PO) dead; reuse as fout
    for (int i = tid; i < 2352; i += 256) {  // 49 rows x 48 float4: x -> fout
        int row = i / 48, c4 = (i % 48) * 4;
        int y  = wy * 7 + row / 7 + 3; if (y >= 56) y -= 56;
        int xx = wx * 7 + row % 7 + 3; if (xx >= 56) xx -= 56;
        const float* xp = x + (size_t)(b * 3136 + y * 56 + xx) * CC + c4;
        *(f32x4*)(fout + row * 196 + c4) = *(const f32x4*)xp;
    }
    __syncthreads();  // x staged
    #pragma unroll
    for (int n = 0; n < 12; ++n) {
        int col = n * 16 + ln16;
        float pb = proj_b[col];
        #pragma unroll
        for (int r = 0; r < 4; ++r) {
            int row = wave * 16 + 4 * sub + r;
            float v = accP[n][r] + pb;
            if (row < 49) {
                v += fout[row * 196 + col];   // unique owner: safe in-place
                fout[row * 196 + col] = v;
            }
            accP[n][r] = v;
        }
    }

    // LN2 from registers (row spans 16 lanes x 12 regs)
    float mu4[4], rs4[4];
    {
        float s[4], qs[4];
        #pragma unroll
        for (int r = 0; r < 4; ++r) { s[r] = 0.f; qs[r] = 0.f; }
        #pragma unroll
        for (int n = 0; n < 12; ++n)
            #pragma unroll
            for (int r = 0; r < 4; ++r) {
                float v = accP[n][r];
                s[r] += v; qs[r] += v * v;
            }
        #pragma unroll
        for (int m = 1; m < 16; m <<= 1) {
            #pragma unroll
            for (int r = 0; r < 4; ++r) {
                s[r]  += __shfl_xor(s[r],  m, 16);
                qs[r] += __shfl_xor(qs[r], m, 16);
            }
        }
        #pragma unroll
        for (int r = 0; r < 4; ++r) {
            float mu = s[r] * (1.0f / 192.0f);
            float var = qs[r] * (1.0f / 192.0f) - mu * mu;
            mu4[r] = mu;
            rs4[r] = rsqrtf(var + 1e-5f);
        }
    }
    __syncthreads();  // all v staged in fout
    for (int i = tid; i < 2352; i += 256) {  // coalesced flush fout -> out
        int row = i / 48, c4 = (i % 48) * 4;
        int y  = wy * 7 + row / 7 + 3; if (y >= 56) y -= 56;
        int xx = wx * 7 + row % 7 + 3; if (xx >= 56) xx -= 56;
        float* op = out + (size_t)(b * 3136 + y * 56 + xx) * CC + c4;
        *(f32x4*)op = *(const f32x4*)(fout + row * 196 + c4);
    }
    __threadfence_block();  // out visible to block for epilogue-B RMW
    __syncthreads();        // flush reads done; fout region reusable as aln

    #pragma unroll
    for (int n = 0; n < 12; ++n) {
        int col = n * 16 + ln16;
        float g = n2g[col], bb = n2b[col];
        #pragma unroll
        for (int r = 0; r < 4; ++r) {
            int row = wave * 16 + 4 * sub + r;
            aln[row * 200 + col] = f2bf((accP[n][r] - mu4[r]) * rs4[r] * g + bb);
        }
    }
    __syncthreads();  // aln ready

    // ---- MLP: 12 x 64-col hidden chunks {FC1, GELU, FC2} ----
    f32x4 accO[4][3];
    #pragma unroll
    for (int m = 0; m < 4; ++m)
        #pragma unroll
        for (int n = 0; n < 3; ++n) accO[m][n] = zero4;

    for (int c = 0; c < 12; ++c) {
        // FC1: wave owns 1 n-tile (16 cols of the 64-col chunk), m_rep=4
        f32x4 acc1[4];
        #pragma unroll
        for (int m = 0; m < 4; ++m) acc1[m] = zero4;
        #pragma unroll
        for (int kk = 0; kk < 6; ++kk) {
            short8 a[4];
            #pragma unroll
            for (int m = 0; m < 4; ++m)
                a[m] = *(const short8*)(aln + (m * 16 + ln16) * 200 + kk * 32 + 8 * sub);
            short8 bb = *(const short8*)(fc1T + (size_t)(c * 64 + wave * 16 + ln16) * 192 + kk * 32 + 8 * sub);
            #pragma unroll
            for (int m = 0; m < 4; ++m) acc1[m] = mfma16(a[m], bb, acc1[m]);
        }
        // GELU + store hid chunk (own cols)
        {
            int cl = wave * 16 + ln16;
            float fb = fc1_b[c * 64 + cl];
            #pragma unroll
            for (int m = 0; m < 4; ++m)
                #pragma unroll
                for (int r = 0; r < 4; ++r) {
                    float hv = acc1[m][r] + fb;
                    hidc[(m * 16 + 4 * sub + r) * 72 + cl] = f2bf(fast_gelu(hv));
                }
        }
        __syncthreads();
        // FC2 partial: k = this chunk's 64 cols (kk 0..1)
        #pragma unroll
        for (int kk = 0; kk < 2; ++kk) {
            short8 a[4];
            #pragma unroll
            for (int m = 0; m < 4; ++m)
                a[m] = *(const short8*)(hidc + (m * 16 + ln16) * 72 + kk * 32 + 8 * sub);
            #pragma unroll
            for (int n = 0; n < 3; ++n) {
                short8 bb = *(const short8*)(fc2T + (size_t)(wave * 48 + n * 16 + ln16) * 768 + c * 64 + kk * 32 + 8 * sub);
                #pragma unroll
                for (int m = 0; m < 4; ++m) accO[m][n] = mfma16(a[m], bb, accO[m][n]);
            }
        }
        __syncthreads();  // WAR on hidc (and on aln at c==11 before fout stage)
    }

    // ---- epilogue B: stage f32 (rows<49), coalesced float4 RMW of out ----
    #pragma unroll
    for (int n = 0; n < 3; ++n) {
        int col = wave * 48 + n * 16 + ln16;
        float fb = fc2_b[col];
        #pragma unroll
        for (int m = 0; m < 4; ++m)
            #pragma unroll
            for (int r = 0; r < 4; ++r) {
                int row = m * 16 + 4 * sub + r;
                if (row < 49) fout[row * 196 + col] = accO[m][n][r] + fb;
            }
    }
    __syncthreads();
    for (int i = tid; i < 2352; i += 256) {  // 49 rows x 48 float4
        int row = i / 48, c4 = (i % 48) * 4;
        int y  = wy * 7 + row / 7 + 3; if (y >= 56) y -= 56;
        int xx = wx * 7 + row % 7 + 3; if (xx >= 56) xx -= 56;
        float* op = out + (size_t)(b * 3136 + y * 56 + xx) * CC + c4;
        f32x4 sv = *(const f32x4*)(fout + row * 196 + c4);
        f32x4 ov = *(const f32x4*)op;
        #pragma unroll
        for (int q = 0; q < 4; ++q) ov[q] += sv[q];
        *(f32x4*)op = ov;
    }
}

// ---------------- fallback: round-2 monolithic attention ----------------
__global__ __launch_bounds__(256, 3) void attn_kernel(
    const float* __restrict__ x, const float* __restrict__ n1g, const float* __restrict__ n1b,
    const float* __restrict__ qkv_b, const float* __restrict__ proj_b,
    const ushort_t* __restrict__ qkvT, const ushort_t* __restrict__ projT,
    const float* __restrict__ biasT, const float* __restrict__ maskT,
    float* __restrict__ out) {
    __shared__ ushort_t xln[64 * 200];
    __shared__ ushort_t qo [64 * 40];
    __shared__ ushort_t kl [64 * 40];
    __shared__ ushort_t vt [32 * 72];
    __shared__ ushort_t Pl [64 * 72];
    const int tid = threadIdx.x;
    const int wave = tid >> 6, lane = tid & 63;
    const int ln16 = lane & 15, sub = lane >> 4;
    const int w = blockIdx.x;
    const int batch = w >> 6, wi = w & 63;
    const int wy = wi >> 3, wx = wi & 7;
    const f32x4 zero4 = {0.f, 0.f, 0.f, 0.f};

    for (int rr = 0; rr < 16; ++rr) {
        int row = wave * 16 + rr;
        if (row < 49) {
            int ty = row / 7, tx = row % 7;
            int y  = wy * 7 + ty + 3; if (y >= 56) y -= 56;
            int xx = wx * 7 + tx + 3; if (xx >= 56) xx -= 56;
            const float* xr = x + (size_t)(batch * 3136 + y * 56 + xx) * CC;
            float v0 = xr[lane], v1 = xr[lane + 64], v2 = xr[lane + 128];
            float s = v0 + v1 + v2;
            #pragma unroll
            for (int m = 32; m; m >>= 1) s += __shfl_xor(s, m);
            float mu = s * (1.0f / 192.0f);
            float d0 = v0 - mu, d1 = v1 - mu, d2 = v2 - mu;
            float q = d0 * d0 + d1 * d1 + d2 * d2;
            #pragma unroll
            for (int m = 32; m; m >>= 1) q += __shfl_xor(q, m);
            float rs = rsqrtf(q * (1.0f / 192.0f) + 1e-5f);
            xln[row * 200 + lane]       = f2bf(d0 * rs * n1g[lane]       + n1b[lane]);
            xln[row * 200 + lane + 64]  = f2bf(d1 * rs * n1g[lane + 64]  + n1b[lane + 64]);
            xln[row * 200 + lane + 128] = f2bf(d2 * rs * n1g[lane + 128] + n1b[lane + 128]);
        } else {
            xln[row * 200 + lane] = 0; xln[row * 200 + lane + 64] = 0; xln[row * 200 + lane + 128] = 0;
        }
    }

    f32x4 accP[12];
    #pragma unroll
    for (int n = 0; n < 12; ++n) accP[n] = zero4;
    const float scale = 0.17677669529663689f;
    const float* mptr = maskT + wi * 2401;

    for (int h = 0; h < 6; ++h) {
        f32x4 acc6[6];
        #pragma unroll
        for (int n = 0; n < 6; ++n) acc6[n] = zero4;
        const int cb0 = h * 32;
        for (int kk = 0; kk < 6; ++kk) {
            short8 a = *(const short8*)(xln + (wave * 16 + ln16) * 200 + kk * 32 + 8 * sub);
            #pragma unroll
            for (int n = 0; n < 6; ++n) {
                int colbase = (n >> 1) * 192 + cb0 + (n & 1) * 16;
                short8 b = *(const short8*)(qkvT + (size_t)(colbase + ln16) * 192 + kk * 32 + 8 * sub);
                acc6[n] = mfma16(a, b, acc6[n]);
            }
        }
        #pragma unroll
        for (int n = 0; n < 6; ++n) {
            int colbase = (n >> 1) * 192 + cb0 + (n & 1) * 16;
            float bv = qkv_b[colbase + ln16];
            int dim = (n & 1) * 16 + ln16;
            #pragma unroll
            for (int r = 0; r < 4; ++r) {
                int row = wave * 16 + 4 * sub + r;
                ushort_t hv = f2bf(acc6[n][r] + bv);
                if (n < 2)      qo[row * 40 + dim] = hv;
                else if (n < 4) kl[row * 40 + dim] = hv;
                else            vt[dim * 72 + row] = hv;
            }
        }
        __syncthreads();

        f32x4 s4[4];
        {
            short8 aq = *(const short8*)(qo + (wave * 16 + ln16) * 40 + 8 * sub);
            #pragma unroll
            for (int n = 0; n < 4; ++n) {
                short8 bk = *(const short8*)(kl + (n * 16 + ln16) * 40 + 8 * sub);
                s4[n] = mfma16(aq, bk, zero4);
            }
        }
        const float* bptr = biasT + h * 2401;
        #pragma unroll
        for (int n = 0; n < 4; ++n) {
            int col = n * 16 + ln16;
            #pragma unroll
            for (int r = 0; r < 4; ++r) {
                int row = wave * 16 + 4 * sub + r;
                s4[n][r] = (row < 49 && col < 49)
                    ? s4[n][r] * scale + bptr[row * 49 + col] + mptr[row * 49 + col]
                    : -1e30f;
            }
        }
        #pragma unroll
        for (int r = 0; r < 4; ++r) {
            float mx = fmaxf(fmaxf(s4[0][r], s4[1][r]), fmaxf(s4[2][r], s4[3][r]));
            mx = fmaxf(mx, __shfl_xor(mx, 1, 16));
            mx = fmaxf(mx, __shfl_xor(mx, 2, 16));
            mx = fmaxf(mx, __shfl_xor(mx, 4, 16));
            mx = fmaxf(mx, __shfl_xor(mx, 8, 16));
            float e0 = __expf(s4[0][r] - mx), e1 = __expf(s4[1][r] - mx);
            float e2 = __expf(s4[2][r] - mx), e3 = __expf(s4[3][r] - mx);
            float sm = e0 + e1 + e2 + e3;
            sm += __shfl_xor(sm, 1, 16);
            sm += __shfl_xor(sm, 2, 16);
            sm += __shfl_xor(sm, 4, 16);
            sm += __shfl_xor(sm, 8, 16);
            float inv = 1.0f / sm;
            int row = wave * 16 + 4 * sub + r;
            Pl[row * 72 +      ln16] = f2bf(e0 * inv);
            Pl[row * 72 + 16 + ln16] = f2bf(e1 * inv);
            Pl[row * 72 + 32 + ln16] = f2bf(e2 * inv);
            Pl[row * 72 + 48 + ln16] = f2bf(e3 * inv);
        }
        f32x4 o2[2]; o2[0] = zero4; o2[1] = zero4;
        #pragma unroll
        for (int ks = 0; ks < 2; ++ks) {
            short8 ap = *(const short8*)(Pl + (wave * 16 + ln16) * 72 + ks * 32 + 8 * sub);
            #pragma unroll
            for (int n2 = 0; n2 < 2; ++n2) {
                short8 bv = *(const short8*)(vt + (n2 * 16 + ln16) * 72 + ks * 32 + 8 * sub);
                o2[n2] = mfma16(ap, bv, o2[n2]);
            }
        }
        #pragma unroll
        for (int n2 = 0; n2 < 2; ++n2)
            #pragma unroll
            for (int r = 0; r < 4; ++r) {
                int row = wave * 16 + 4 * sub + r;
                qo[row * 40 + n2 * 16 + ln16] = f2bf(o2[n2][r]);
            }
        {
            short8 ao = *(const short8*)(qo + (wave * 16 + ln16) * 40 + 8 * sub);
            #pragma unroll
            for (int n = 0; n < 12; ++n) {
                short8 bp = *(const short8*)(projT + (size_t)(n * 16 + ln16) * 192 + h * 32 + 8 * sub);
                accP[n] = mfma16(ao, bp, accP[n]);
            }
        }
        __syncthreads();
    }

    #pragma unroll
    for (int n = 0; n < 12; ++n) {
        int col = n * 16 + ln16;
        float pb = proj_b[col];
        #pragma unroll
        for (int r = 0; r < 4; ++r) {
            int row = wave * 16 + 4 * sub + r;
            if (row < 49) {
                int ty = row / 7, tx = row % 7;
                int y  = wy * 7 + ty + 3; if (y >= 56) y -= 56;
                int xx = wx * 7 + tx + 3; if (xx >= 56) xx -= 56;
                size_t g = (size_t)(batch * 3136 + y * 56 + xx) * CC;
                out[g + col] = accP[n][r] + pb + x[g + col];
            }
        }
    }
}

// ---------------- fallback MLP (round-7 mlp5) ----------------
__global__ __launch_bounds__(256, 3) void mlp5_kernel(
    float* __restrict__ out, const float* __restrict__ n2g, const float* __restrict__ n2b,
    const float* __restrict__ fc1_b, const float* __restrict__ fc2_b,
    const ushort_t* __restrict__ fc1T, const ushort_t* __restrict__ fc2T) {
    __shared__ ushort_t smem[2][64 * 200];
    ushort_t* aln  = smem[0];
    ushort_t* hidc = smem[1];
    float* fout = (float*)&smem[0][0];
    const int tid = threadIdx.x;
    const int wave = tid >> 6, lane = tid & 63;
    const int ln16 = lane & 15, sub = lane >> 4;
    const size_t t0 = (size_t)blockIdx.x * 64;
    const f32x4 zero4 = {0.f, 0.f, 0.f, 0.f};

    short8 b1p[3];
    #pragma unroll
    for (int n = 0; n < 3; ++n)
        b1p[n] = *(const short8*)(fc1T + (size_t)(wave * 48 + n * 16 + ln16) * 192 + 8 * sub);

    {
        float g0 = n2g[lane], g1 = n2g[lane + 64], g2 = n2g[lane + 128];
        float bb0 = n2b[lane], bb1 = n2b[lane + 64], bb2 = n2b[lane + 128];
        for (int rb = 0; rb < 4; ++rb) {
            int row0 = wave * 16 + rb * 4;
            float v0[4], v1[4], v2[4], s[4], q[4];
            #pragma unroll
            for (int j = 0; j < 4; ++j) {
                const float* xr = out + (t0 + row0 + j) * CC;
                v0[j] = xr[lane]; v1[j] = xr[lane + 64]; v2[j] = xr[lane + 128];
            }
            #pragma unroll
            for (int j = 0; j < 4; ++j) {
                s[j] = v0[j] + v1[j] + v2[j];
                q[j] = v0[j] * v0[j] + v1[j] * v1[j] + v2[j] * v2[j];
            }
            #pragma unroll
            for (int m = 32; m; m >>= 1) {
                #pragma unroll
                for (int j = 0; j < 4; ++j) { s[j] += __shfl_xor(s[j], m); q[j] += __shfl_xor(q[j], m); }
            }
            #pragma unroll
            for (int j = 0; j < 4; ++j) {
                float mu = s[j] * (1.0f / 192.0f);
                float var = q[j] * (1.0f / 192.0f) - mu * mu;
                float rs = rsqrtf(var + 1e-5f);
                int row = row0 + j;
                aln[row * 200 + lane]       = f2bf((v0[j] - mu) * rs * g0 + bb0);
                aln[row * 200 + lane + 64]  = f2bf((v1[j] - mu) * rs * g1 + bb1);
                aln[row * 200 + lane + 128] = f2bf((v2[j] - mu) * rs * g2 + bb2);
            }
        }
    }
    __syncthreads();

    f32x4 accO[4][3];
    #pragma unroll
    for (int m = 0; m < 4; ++m)
        #pragma unroll
        for (int n = 0; n < 3; ++n) accO[m][n] = zero4;

    for (int c = 0; c < 4; ++c) {
        f32x4 acc1[4][3];
        #pragma unroll
        for (int m = 0; m < 4; ++m)
            #pragma unroll
            for (int n = 0; n < 3; ++n) acc1[m][n] = zero4;
        #pragma unroll
        for (int kk = 0; kk < 6; ++kk) {
            short8 a[4];
            #pragma unroll
            for (int m = 0; m < 4; ++m)
                a[m] = *(const short8*)(aln + (m * 16 + ln16) * 200 + kk * 32 + 8 * sub);
            short8 bb[3];
            if (kk == 0) {
                bb[0] = b1p[0]; bb[1] = b1p[1]; bb[2] = b1p[2];
            } else {
                #pragma unroll
                for (int n = 0; n < 3; ++n)
                    bb[n] = *(const short8*)(fc1T + (size_t)(c * 192 + wave * 48 + n * 16 + ln16) * 192 + kk * 32 + 8 * sub);
            }
            #pragma unroll
            for (int n = 0; n < 3; ++n)
                #pragma unroll
                for (int m = 0; m < 4; ++m) acc1[m][n] = mfma16(a[m], bb[n], acc1[m][n]);
        }
        short8 b2p[3];
        #pragma unroll
        for (int n = 0; n < 3; ++n)
            b2p[n] = *(const short8*)(fc2T + (size_t)(wave * 48 + n * 16 + ln16) * 768 + c * 192 + 8 * sub);
        if (c < 3) {
            #pragma unroll
            for (int n = 0; n < 3; ++n)
                b1p[n] = *(const short8*)(fc1T + (size_t)((c + 1) * 192 + wave * 48 + n * 16 + ln16) * 192 + 8 * sub);
        }
        #pragma unroll
        for (int n = 0; n < 3; ++n) {
            int cl = wave * 48 + n * 16 + ln16;
            float fb = fc1_b[c * 192 + cl];
            #pragma unroll
            for (int m = 0; m < 4; ++m)
                #pragma unroll
                for (int r = 0; r < 4; ++r) {
                    float hv = acc1[m][n][r] + fb;
                    hidc[(m * 16 + 4 * sub + r) * 200 + cl] = f2bf(fast_gelu(hv));
                }
        }
        __syncthreads();
        #pragma unroll
        for (int kk = 0; kk < 6; ++kk) {
            short8 a[4];
            #pragma unroll
            for (int m = 0; m < 4; ++m)
                a[m] = *(const short8*)(hidc + (m * 16 + ln16) * 200 + kk * 32 + 8 * sub);
            short8 bb[3];
            if (kk == 0) {
                bb[0] = b2p[0]; bb[1] = b2p[1]; bb[2] = b2p[2];
            } else {
                #pragma unroll
                for (int n = 0; n < 3; ++n)
                    bb[n] = *(const short8*)(fc2T + (size_t)(wave * 48 + n * 16 + ln16) * 768 + c * 192 + kk * 32 + 8 * sub);
            }
            #pragma unroll
            for (int n = 0; n < 3; ++n)
                #pragma unroll
                for (int m = 0; m < 4; ++m) accO[m][n] = mfma16(a[m], bb[n], accO[m][n]);
        }
        __syncthreads();
    }

    #pragma unroll
    for (int n = 0; n < 3; ++n) {
        int col = wave * 48 + n * 16 + ln16;
        float fb = fc2_b[col];
        #pragma unroll
        for (int m = 0; m < 4; ++m)
            #pragma unroll
            for (int r = 0; r < 4; ++r)
                fout[(m * 16 + 4 * sub + r) * 196 + col] = accO[m][n][r] + fb;
    }
    __syncthreads();
    for (int i = tid; i < 3072; i += 256) {
        int row = i / 48, c4 = (i % 48) * 4;
        f32x4 sv = *(const f32x4*)(fout + row * 196 + c4);
        float* op = out + (t0 + row) * CC + c4;
        f32x4 ov = *(const f32x4*)op;
        #pragma unroll
        for (int q = 0; q < 4; ++q) ov[q] += sv[q];
        *(f32x4*)op = ov;
    }
}

// ---------------- launch ----------------
extern "C" void kernel_launch(void* const* d_in, const int* in_sizes, int n_in,
                              void* d_out, int out_size, void* d_ws, size_t ws_size,
                              hipStream_t stream) {
    const float* x      = (const float*)d_in[0];
    const float* n1g    = (const float*)d_in[1];
    const float* n1b    = (const float*)d_in[2];
    const float* qkv_w  = (const float*)d_in[3];
    const float* qkv_b  = (const float*)d_in[4];
    const float* rel_t  = (const float*)d_in[5];
    const float* proj_w = (const float*)d_in[6];
    const float* proj_b = (const float*)d_in[7];
    const float* n2g    = (const float*)d_in[8];
    const float* n2b    = (const float*)d_in[9];
    const float* fc1_w  = (const float*)d_in[10];
    const float* fc1_b  = (const float*)d_in[11];
    const float* fc2_w  = (const float*)d_in[12];
    const float* fc2_b  = (const float*)d_in[13];
    float* out = (float*)d_out;

    char* ws = (char*)d_ws;
    ushort_t* qkvT  = (ushort_t*)(ws + OFF_QKVT);
    ushort_t* projT = (ushort_t*)(ws + OFF_PROJT);
    ushort_t* fc1T  = (ushort_t*)(ws + OFF_FC1T);
    ushort_t* fc2T  = (ushort_t*)(ws + OFF_FC2T);
    float* biasT    = (float*)(ws + OFF_BIAS);
    float* maskT    = (float*)(ws + OFF_MASK);
    float* bmT      = (float*)(ws + OFF_BMT);
    ushort_t* qg    = (ushort_t*)(ws + OFF_QG);
    ushort_t* kg    = (ushort_t*)(ws + OFF_KG);
    ushort_t* vg    = (ushort_t*)(ws + OFF_VG);

    const int big = ws_size >= (size_t)WS_NEED;
    const int prep_total = big ? PREP_BIG : PREP_SMALL;
    prep_kernel<<<(prep_total + 255) / 256, 256, 0, stream>>>(
        qkv_w, proj_w, fc1_w, fc2_w, rel_t, qkvT, projT, fc1T, fc2T, biasT, maskT, bmT, big);

    if (big) {
        lnqkv_kernel<<<1568, 256, 0, stream>>>(x, n1g, n1b, qkvT, qkv_b, qg, kg, vg);
        attnmlp_kernel<<<2048, 256, 0, stream>>>(x, proj_b, qg, kg, vg, projT, bmT,
                                                 n2g, n2b, fc1_b, fc2_b, fc1T, fc2T, out);
    } else {
        attn_kernel<<<2048, 256, 0, stream>>>(x, n1g, n1b, qkv_b, proj_b,
                                              qkvT, projT, biasT, maskT, out);
        mlp5_kernel<<<1568, 256, 0, stream>>>(out, n2g, n2b, fc1_b, fc2_b, fc1T, fc2T);
    }
}

// Round 19
// 359.832 us; speedup vs baseline: 1.0199x; 1.0199x over previous
//
#include <hip/hip_runtime.h>
#include <hip/hip_bf16.h>

// Swin block, round 19 = exact revert to round 17 (verified best, 362.3 us).
//  - r18's no-max softmax regressed (+5 us, WRITE 161->169 MB): the max
//    shuffle chain was free under TLP and removing it perturbed codegen.
//  - Ledger closed: adopted {fused attn+LN2+MLP, coalesced LDS-staged
//    epilogues, fast GELU, 38.4KB LDS -> 4 blocks/CU, no setprio};
//    refuted {reg pipelines (64-VGPR wall x3), waves_per_eu, A-frag cache,
//    no-max softmax, attn setprio}.
//  - fallback: round-2 attn + round-7 mlp5 if ws too small.

using f32x4  = __attribute__((ext_vector_type(4))) float;
using short8 = __attribute__((ext_vector_type(8))) short;
typedef unsigned short ushort_t;

__device__ __forceinline__ ushort_t f2bf(float f) {
    __hip_bfloat16 h = __float2bfloat16(f);
    return __builtin_bit_cast(ushort_t, h);
}
__device__ __forceinline__ f32x4 mfma16(short8 a, short8 b, f32x4 c) {
    return __builtin_amdgcn_mfma_f32_16x16x32_bf16(a, b, c, 0, 0, 0);
}
// gelu(h) ~= h * sigmoid(1.5957691*h*(1+0.044715*h^2)); saturation-safe.
__device__ __forceinline__ float fast_gelu(float h) {
    float hh = h * h;
    float p  = __builtin_fmaf(hh, 0.044715f, 1.0f);
    float z  = h * (-1.5957691216057308f);
    float em = __expf(p * z);
    return h * __builtin_amdgcn_rcpf(1.0f + em);
}

#define CC 192

// ws offsets (bytes)
#define OFF_QKVT   0          // [576][192] bf16
#define OFF_PROJT  221184     // [192][192] bf16
#define OFF_FC1T   294912     // [768][192] bf16
#define OFF_FC2T   589824     // [192][768] bf16
#define OFF_BIAS   884736     // [6][49][49] f32
#define OFF_MASK   942592     // [64][49][49] f32
#define OFF_BMT    1557504    // [64][6][64][64] f32 (bias+mask, transposed, pad=-1e30)
#define OFF_QG     7848960    // [100352][192] bf16 (scaled Q)
#define OFF_KG     46384128   // [100352][192] bf16
#define OFF_VG     84919296   // [100352][192] bf16
#define WS_NEED    123454464
#define PREP_SMALL 610438
#define PREP_BIG   2183302

// ---------------- prep ----------------
__global__ void prep_kernel(const float* __restrict__ qkv_w, const float* __restrict__ proj_w,
                            const float* __restrict__ fc1_w, const float* __restrict__ fc2_w,
                            const float* __restrict__ rel_table,
                            ushort_t* __restrict__ qkvT, ushort_t* __restrict__ projT,
                            ushort_t* __restrict__ fc1T, ushort_t* __restrict__ fc2T,
                            float* __restrict__ biasT, float* __restrict__ maskT,
                            float* __restrict__ bmT, int full) {
    int idx = blockIdx.x * 256 + threadIdx.x;
    if (idx < 110592) { int n = idx / 192, k = idx % 192; qkvT[idx] = f2bf(qkv_w[k * 576 + n]); return; }
    idx -= 110592;
    if (idx < 36864) { int n = idx / 192, k = idx % 192; projT[idx] = f2bf(proj_w[k * 192 + n]); return; }
    idx -= 36864;
    if (idx < 147456) { int n = idx / 192, k = idx % 192; fc1T[idx] = f2bf(fc1_w[k * 768 + n]); return; }
    idx -= 147456;
    if (idx < 147456) { int n = idx / 768, k = idx % 768; fc2T[idx] = f2bf(fc2_w[k * 192 + n]); return; }
    idx -= 147456;
    if (idx < 14406) {
        int h = idx / 2401; int rest = idx % 2401; int a = rest / 49, b = rest % 49;
        int d = 13 * ((a % 7) - (b % 7) + (a / 7) - (b / 7) + 12);
        if (d > 168) d = 168;
        biasT[idx] = rel_table[d * 6 + h];
        return;
    }
    idx -= 14406;
    if (idx < 153664) {
        int w = idx / 2401; int rest = idx % 2401; int a = rest / 49, b = rest % 49;
        int wy = w / 8, wx = w % 8;
        int ya = wy * 7 + a / 7, xa = wx * 7 + a % 7;
        int yb = wy * 7 + b / 7, xb = wx * 7 + b % 7;
        int lya = ya < 49 ? 0 : (ya < 53 ? 1 : 2);
        int lxa = xa < 49 ? 0 : (xa < 53 ? 1 : 2);
        int lyb = yb < 49 ? 0 : (yb < 53 ? 1 : 2);
        int lxb = xb < 49 ? 0 : (xb < 53 ? 1 : 2);
        maskT[idx] = ((lya * 3 + lxa) != (lyb * 3 + lxb)) ? -100.0f : 0.0f;
        return;
    }
    idx -= 153664;
    if (full && idx < 1572864) {  // bmT[wi][h][col][row]
        int wi = idx / 24576; int r2 = idx % 24576;
        int h = r2 / 4096; int r3 = r2 % 4096;
        int col = r3 / 64, row = r3 % 64;
        float v = -1e30f;
        if (row < 49 && col < 49) {
            int d = 13 * ((row % 7) - (col % 7) + (row / 7) - (col / 7) + 12);
            if (d > 168) d = 168;
            float bias = rel_table[d * 6 + h];
            int wy = wi / 8, wx = wi % 8;
            int ya = wy * 7 + row / 7, xa = wx * 7 + row % 7;
            int yb = wy * 7 + col / 7, xb = wx * 7 + col % 7;
            int lya = ya < 49 ? 0 : (ya < 53 ? 1 : 2);
            int lxa = xa < 49 ? 0 : (xa < 53 ? 1 : 2);
            int lyb = yb < 49 ? 0 : (yb < 53 ? 1 : 2);
            int lxb = xb < 49 ? 0 : (xb < 53 ? 1 : 2);
            float mask = ((lya * 3 + lxa) != (lyb * 3 + lxb)) ? -100.0f : 0.0f;
            v = bias + mask;
        }
        bmT[idx] = v;
        return;
    }
}

// ---------------- phase A: LN1 + QKV GEMM, coalesced writes ----------------
__global__ __launch_bounds__(256, 3) void lnqkv_kernel(
    const float* __restrict__ x, const float* __restrict__ n1g, const float* __restrict__ n1b,
    const ushort_t* __restrict__ qkvT, const float* __restrict__ qkv_b,
    ushort_t* __restrict__ qg, ushort_t* __restrict__ kg, ushort_t* __restrict__ vg) {
    __shared__ ushort_t xln [64 * 200];
    __shared__ ushort_t qkvs[64 * 200];
    const int tid = threadIdx.x;
    const int wave = tid >> 6, lane = tid & 63;
    const int ln16 = lane & 15, sub = lane >> 4;
    const int t0 = blockIdx.x * 64;
    const f32x4 zero4 = {0.f, 0.f, 0.f, 0.f};

    {
        float g0 = n1g[lane], g1 = n1g[lane + 64], g2 = n1g[lane + 128];
        float bb0 = n1b[lane], bb1 = n1b[lane + 64], bb2 = n1b[lane + 128];
        for (int rb = 0; rb < 4; ++rb) {
            int row0 = wave * 16 + rb * 4;
            float v0[4], v1[4], v2[4], s[4], q[4];
            #pragma unroll
            for (int j = 0; j < 4; ++j) {
                const float* xr = x + (size_t)(t0 + row0 + j) * CC;
                v0[j] = xr[lane]; v1[j] = xr[lane + 64]; v2[j] = xr[lane + 128];
            }
            #pragma unroll
            for (int j = 0; j < 4; ++j) {
                s[j] = v0[j] + v1[j] + v2[j];
                q[j] = v0[j] * v0[j] + v1[j] * v1[j] + v2[j] * v2[j];
            }
            #pragma unroll
            for (int m = 32; m; m >>= 1) {
                #pragma unroll
                for (int j = 0; j < 4; ++j) { s[j] += __shfl_xor(s[j], m); q[j] += __shfl_xor(q[j], m); }
            }
            #pragma unroll
            for (int j = 0; j < 4; ++j) {
                float mu = s[j] * (1.0f / 192.0f);
                float var = q[j] * (1.0f / 192.0f) - mu * mu;
                float rs = rsqrtf(var + 1e-5f);
                int row = row0 + j;
                xln[row * 200 + lane]       = f2bf((v0[j] - mu) * rs * g0 + bb0);
                xln[row * 200 + lane + 64]  = f2bf((v1[j] - mu) * rs * g1 + bb1);
                xln[row * 200 + lane + 128] = f2bf((v2[j] - mu) * rs * g2 + bb2);
            }
        }
    }
    __syncthreads();

    ushort_t* dsts[3] = {qg, kg, vg};
    for (int v = 0; v < 3; ++v) {
        f32x4 acc[4][3];
        #pragma unroll
        for (int m = 0; m < 4; ++m)
            #pragma unroll
            for (int n = 0; n < 3; ++n) acc[m][n] = zero4;
        for (int kk = 0; kk < 6; ++kk) {
            short8 a[4];
            #pragma unroll
            for (int m = 0; m < 4; ++m)
                a[m] = *(const short8*)(xln + (m * 16 + ln16) * 200 + kk * 32 + 8 * sub);
            #pragma unroll
            for (int n = 0; n < 3; ++n) {
                short8 b = *(const short8*)(qkvT + (size_t)(v * 192 + (wave * 3 + n) * 16 + ln16) * 192 + kk * 32 + 8 * sub);
                #pragma unroll
                for (int m = 0; m < 4; ++m) acc[m][n] = mfma16(a[m], b, acc[m][n]);
            }
        }
        #pragma unroll
        for (int n = 0; n < 3; ++n) {
            int col = (wave * 3 + n) * 16 + ln16;
            float bv = qkv_b[v * 192 + col];
            #pragma unroll
            for (int m = 0; m < 4; ++m)
                #pragma unroll
                for (int r = 0; r < 4; ++r) {
                    int row = m * 16 + 4 * sub + r;
                    float val = acc[m][n][r] + bv;
                    if (v == 0) val *= 0.17677669529663689f;
                    qkvs[row * 200 + col] = f2bf(val);
                }
        }
        __syncthreads();
        ushort_t* dst = dsts[v];
        for (int i = tid; i < 1536; i += 256) {
            int row = i / 24, c = i % 24;
            short8 vv = *(const short8*)(qkvs + row * 200 + c * 8);
            *(short8*)(dst + (size_t)(t0 + row) * 192 + c * 8) = vv;
        }
        __syncthreads();
    }
}

// ---------------- phase B: FUSED attention + LN2 + MLP, v6-nosetprio ------
// 1 block/window (2048), 4 waves, 38.4 KB LDS -> 4 blocks/CU.
__global__ __launch_bounds__(256, 4) void attnmlp_kernel(
    const float* __restrict__ x, const float* __restrict__ proj_b,
    const ushort_t* __restrict__ qg, const ushort_t* __restrict__ kg,
    const ushort_t* __restrict__ vg, const ushort_t* __restrict__ projT,
    const float* __restrict__ bmT,
    const float* __restrict__ n2g, const float* __restrict__ n2b,
    const float* __restrict__ fc1_b, const float* __restrict__ fc2_b,
    const ushort_t* __restrict__ fc1T, const ushort_t* __restrict__ fc2T,
    float* __restrict__ out) {
    __shared__ __align__(16) char smem[38416];
    ushort_t* vt   = (ushort_t*)smem;            // attn: [192][72]  (27,648)
    ushort_t* PO   = (ushort_t*)(smem + 27648);  // attn: [4][16*72] ( 9,216)
    ushort_t* aln  = (ushort_t*)smem;            // mlp:  [64][200]  (25,600)
    ushort_t* hidc = (ushort_t*)(smem + 25600);  // mlp:  [64][72]   ( 9,216)
    float*    fout = (float*)smem;               // stage:[49][196]  (38,416)

    const int tid = threadIdx.x;
    const int wave = tid >> 6, lane = tid & 63;
    const int ln16 = lane & 15, sub = lane >> 4;
    const int win = blockIdx.x;
    const int b = win >> 6, wi = win & 63;
    const int wy = wi >> 3, wx = wi & 7;
    const f32x4 zero4 = {0.f, 0.f, 0.f, 0.f};

    size_t tokA;
    {
        int j = wave * 16 + ln16; if (j > 48) j = 48;
        int y  = wy * 7 + j / 7 + 3; if (y >= 56) y -= 56;
        int xx = wx * 7 + j % 7 + 3; if (xx >= 56) xx -= 56;
        tokA = (size_t)(b * 3136 + y * 56 + xx);
    }
    size_t tokB[4];
    #pragma unroll
    for (int n = 0; n < 4; ++n) {
        int j = n * 16 + ln16; if (j > 48) j = 48;
        int y  = wy * 7 + j / 7 + 3; if (y >= 56) y -= 56;
        int xx = wx * 7 + j % 7 + 3; if (xx >= 56) xx -= 56;
        tokB[n] = (size_t)(b * 3136 + y * 56 + xx);
    }
    const float* bmw = bmT + (size_t)wi * 24576 + (size_t)(wave * 16 + 4 * sub);

    // ---- stage V^T for this window ----
    {
        int j = tid & 63;
        int jj = j < 49 ? j : 48;
        int y  = wy * 7 + jj / 7 + 3; if (y >= 56) y -= 56;
        int xx = wx * 7 + jj % 7 + 3; if (xx >= 56) xx -= 56;
        size_t tokV = (size_t)(b * 3136 + y * 56 + xx);
        const bool valid = j < 49;
        #pragma unroll
        for (int pass = 0; pass < 6; ++pass) {
            int c8 = pass * 32 + (tid >> 6) * 8;
            if (valid) {
                short8 vv = *(const short8*)(vg + tokV * 192 + c8);
                #pragma unroll
                for (int q = 0; q < 8; ++q) vt[(c8 + q) * 72 + j] = ((ushort_t*)&vv)[q];
            } else {
                #pragma unroll
                for (int q = 0; q < 8; ++q) vt[(c8 + q) * 72 + j] = 0;
            }
        }
    }

    f32x4 accP[12];
    #pragma unroll
    for (int n = 0; n < 12; ++n) accP[n] = zero4;
    ushort_t* Pw = PO + wave * (16 * 72);
    __syncthreads();  // vt ready

    for (int h = 0; h < 6; ++h) {
        // per-head loads (no cross-head pipeline; TLP hides latency)
        short8 qf = *(const short8*)(qg + tokA * 192 + h * 32 + 8 * sub);
        short8 kf[4];
        f32x4  bv[4];
        #pragma unroll
        for (int n = 0; n < 4; ++n) {
            kf[n] = *(const short8*)(kg + tokB[n] * 192 + h * 32 + 8 * sub);
            bv[n] = *(const f32x4*)(bmw + h * 4096 + (n * 16 + ln16) * 64);
        }
        f32x4 s4[4];
        #pragma unroll
        for (int n = 0; n < 4; ++n) s4[n] = mfma16(qf, kf[n], zero4);
        #pragma unroll
        for (int n = 0; n < 4; ++n)
            #pragma unroll
            for (int r = 0; r < 4; ++r) s4[n][r] += bv[n][r];
        #pragma unroll
        for (int r = 0; r < 4; ++r) {
            float mx = fmaxf(fmaxf(s4[0][r], s4[1][r]), fmaxf(s4[2][r], s4[3][r]));
            mx = fmaxf(mx, __shfl_xor(mx, 1, 16));
            mx = fmaxf(mx, __shfl_xor(mx, 2, 16));
            mx = fmaxf(mx, __shfl_xor(mx, 4, 16));
            mx = fmaxf(mx, __shfl_xor(mx, 8, 16));
            float e0 = __expf(s4[0][r] - mx), e1 = __expf(s4[1][r] - mx);
            float e2 = __expf(s4[2][r] - mx), e3 = __expf(s4[3][r] - mx);
            float sm = e0 + e1 + e2 + e3;
            sm += __shfl_xor(sm, 1, 16);
            sm += __shfl_xor(sm, 2, 16);
            sm += __shfl_xor(sm, 4, 16);
            sm += __shfl_xor(sm, 8, 16);
            float inv = 1.0f / sm;
            int rl = 4 * sub + r;
            Pw[rl * 72 +      ln16] = f2bf(e0 * inv);
            Pw[rl * 72 + 16 + ln16] = f2bf(e1 * inv);
            Pw[rl * 72 + 32 + ln16] = f2bf(e2 * inv);
            Pw[rl * 72 + 48 + ln16] = f2bf(e3 * inv);
        }
        short8 ap0 = *(const short8*)(Pw + ln16 * 72 + 8 * sub);
        short8 ap1 = *(const short8*)(Pw + ln16 * 72 + 32 + 8 * sub);
        f32x4 o2[2]; o2[0] = zero4; o2[1] = zero4;
        #pragma unroll
        for (int n2 = 0; n2 < 2; ++n2) {
            short8 bv0 = *(const short8*)(vt + (h * 32 + n2 * 16 + ln16) * 72 + 8 * sub);
            short8 bv1 = *(const short8*)(vt + (h * 32 + n2 * 16 + ln16) * 72 + 32 + 8 * sub);
            o2[n2] = mfma16(ap0, bv0, o2[n2]);
            o2[n2] = mfma16(ap1, bv1, o2[n2]);
        }
        #pragma unroll
        for (int n2 = 0; n2 < 2; ++n2)
            #pragma unroll
            for (int r = 0; r < 4; ++r)
                Pw[(4 * sub + r) * 72 + n2 * 16 + ln16] = f2bf(o2[n2][r]);
        {
            short8 ao = *(const short8*)(Pw + ln16 * 72 + 8 * sub);
            #pragma unroll
            for (int n = 0; n < 12; ++n) {
                short8 bp = *(const short8*)(projT + (size_t)(n * 16 + ln16) * 192 + h * 32 + 8 * sub);
                accP[n] = mfma16(ao, bp, accP[n]);
            }
        }
    }

    // ---- epilogue A (coalesced): stage x into dead attn LDS, add resid,
    //      write v back to uniquely-owned slots, flush float4 to out ----
    __syncthreads();  // attn LDS (vt/PO) dead; reuse as fout
    for (int i = tid; i < 2352; i += 256) {  // 49 rows x 48 float4: x -> fout
        int row = i / 48, c4 = (i % 48) * 4;
        int y  = wy * 7 + row / 7 + 3; if (y >= 56) y -= 56;
        int xx = wx * 7 + row % 7 + 3; if (xx >= 56) xx -= 56;
        const float* xp = x + (size_t)(b * 3136 + y * 56 + xx) * CC + c4;
        *(f32x4*)(fout + row * 196 + c4) = *(const f32x4*)xp;
    }
    __syncthreads();  // x staged
    #pragma unroll
    for (int n = 0; n < 12; ++n) {
        int col = n * 16 + ln16;
        float pb = proj_b[col];
        #pragma unroll
        for (int r = 0; r < 4; ++r) {
            int row = wave * 16 + 4 * sub + r;
            float v = accP[n][r] + pb;
            if (row < 49) {
                v += fout[row * 196 + col];   // unique owner: safe in-place
                fout[row * 196 + col] = v;
            }
            accP[n][r] = v;
        }
    }

    // LN2 from registers (row spans 16 lanes x 12 regs)
    float mu4[4], rs4[4];
    {
        float s[4], qs[4];
        #pragma unroll
        for (int r = 0; r < 4; ++r) { s[r] = 0.f; qs[r] = 0.f; }
        #pragma unroll
        for (int n = 0; n < 12; ++n)
            #pragma unroll
            for (int r = 0; r < 4; ++r) {
                float v = accP[n][r];
                s[r] += v; qs[r] += v * v;
            }
        #pragma unroll
        for (int m = 1; m < 16; m <<= 1) {
            #pragma unroll
            for (int r = 0; r < 4; ++r) {
                s[r]  += __shfl_xor(s[r],  m, 16);
                qs[r] += __shfl_xor(qs[r], m, 16);
            }
        }
        #pragma unroll
        for (int r = 0; r < 4; ++r) {
            float mu = s[r] * (1.0f / 192.0f);
            float var = qs[r] * (1.0f / 192.0f) - mu * mu;
            mu4[r] = mu;
            rs4[r] = rsqrtf(var + 1e-5f);
        }
    }
    __syncthreads();  // all v staged in fout
    for (int i = tid; i < 2352; i += 256) {  // coalesced flush fout -> out
        int row = i / 48, c4 = (i % 48) * 4;
        int y  = wy * 7 + row / 7 + 3; if (y >= 56) y -= 56;
        int xx = wx * 7 + row % 7 + 3; if (xx >= 56) xx -= 56;
        float* op = out + (size_t)(b * 3136 + y * 56 + xx) * CC + c4;
        *(f32x4*)op = *(const f32x4*)(fout + row * 196 + c4);
    }
    __threadfence_block();  // out visible to block for epilogue-B RMW
    __syncthreads();        // flush reads done; fout region reusable as aln

    #pragma unroll
    for (int n = 0; n < 12; ++n) {
        int col = n * 16 + ln16;
        float g = n2g[col], bb = n2b[col];
        #pragma unroll
        for (int r = 0; r < 4; ++r) {
            int row = wave * 16 + 4 * sub + r;
            aln[row * 200 + col] = f2bf((accP[n][r] - mu4[r]) * rs4[r] * g + bb);
        }
    }
    __syncthreads();  // aln ready

    // ---- MLP: 12 x 64-col hidden chunks {FC1, GELU, FC2} ----
    f32x4 accO[4][3];
    #pragma unroll
    for (int m = 0; m < 4; ++m)
        #pragma unroll
        for (int n = 0; n < 3; ++n) accO[m][n] = zero4;

    for (int c = 0; c < 12; ++c) {
        // FC1: wave owns 1 n-tile (16 cols of the 64-col chunk), m_rep=4
        f32x4 acc1[4];
        #pragma unroll
        for (int m = 0; m < 4; ++m) acc1[m] = zero4;
        #pragma unroll
        for (int kk = 0; kk < 6; ++kk) {
            short8 a[4];
            #pragma unroll
            for (int m = 0; m < 4; ++m)
                a[m] = *(const short8*)(aln + (m * 16 + ln16) * 200 + kk * 32 + 8 * sub);
            short8 bb = *(const short8*)(fc1T + (size_t)(c * 64 + wave * 16 + ln16) * 192 + kk * 32 + 8 * sub);
            #pragma unroll
            for (int m = 0; m < 4; ++m) acc1[m] = mfma16(a[m], bb, acc1[m]);
        }
        // GELU + store hid chunk (own cols)
        {
            int cl = wave * 16 + ln16;
            float fb = fc1_b[c * 64 + cl];
            #pragma unroll
            for (int m = 0; m < 4; ++m)
                #pragma unroll
                for (int r = 0; r < 4; ++r) {
                    float hv = acc1[m][r] + fb;
                    hidc[(m * 16 + 4 * sub + r) * 72 + cl] = f2bf(fast_gelu(hv));
                }
        }
        __syncthreads();
        // FC2 partial: k = this chunk's 64 cols (kk 0..1)
        #pragma unroll
        for (int kk = 0; kk < 2; ++kk) {
            short8 a[4];
            #pragma unroll
            for (int m = 0; m < 4; ++m)
                a[m] = *(const short8*)(hidc + (m * 16 + ln16) * 72 + kk * 32 + 8 * sub);
            #pragma unroll
            for (int n = 0; n < 3; ++n) {
                short8 bb = *(const short8*)(fc2T + (size_t)(wave * 48 + n * 16 + ln16) * 768 + c * 64 + kk * 32 + 8 * sub);
                #pragma unroll
                for (int m = 0; m < 4; ++m) accO[m][n] = mfma16(a[m], bb, accO[m][n]);
            }
        }
        __syncthreads();  // WAR on hidc (and on aln at c==11 before fout stage)
    }

    // ---- epilogue B: stage f32 (rows<49), coalesced float4 RMW of out ----
    #pragma unroll
    for (int n = 0; n < 3; ++n) {
        int col = wave * 48 + n * 16 + ln16;
        float fb = fc2_b[col];
        #pragma unroll
        for (int m = 0; m < 4; ++m)
            #pragma unroll
            for (int r = 0; r < 4; ++r) {
                int row = m * 16 + 4 * sub + r;
                if (row < 49) fout[row * 196 + col] = accO[m][n][r] + fb;
            }
    }
    __syncthreads();
    for (int i = tid; i < 2352; i += 256) {  // 49 rows x 48 float4
        int row = i / 48, c4 = (i % 48) * 4;
        int y  = wy * 7 + row / 7 + 3; if (y >= 56) y -= 56;
        int xx = wx * 7 + row % 7 + 3; if (xx >= 56) xx -= 56;
        float* op = out + (size_t)(b * 3136 + y * 56 + xx) * CC + c4;
        f32x4 sv = *(const f32x4*)(fout + row * 196 + c4);
        f32x4 ov = *(const f32x4*)op;
        #pragma unroll
        for (int q = 0; q < 4; ++q) ov[q] += sv[q];
        *(f32x4*)op = ov;
    }
}

// ---------------- fallback: round-2 monolithic attention ----------------
__global__ __launch_bounds__(256, 3) void attn_kernel(
    const float* __restrict__ x, const float* __restrict__ n1g, const float* __restrict__ n1b,
    const float* __restrict__ qkv_b, const float* __restrict__ proj_b,
    const ushort_t* __restrict__ qkvT, const ushort_t* __restrict__ projT,
    const float* __restrict__ biasT, const float* __restrict__ maskT,
    float* __restrict__ out) {
    __shared__ ushort_t xln[64 * 200];
    __shared__ ushort_t qo [64 * 40];
    __shared__ ushort_t kl [64 * 40];
    __shared__ ushort_t vt [32 * 72];
    __shared__ ushort_t Pl [64 * 72];
    const int tid = threadIdx.x;
    const int wave = tid >> 6, lane = tid & 63;
    const int ln16 = lane & 15, sub = lane >> 4;
    const int w = blockIdx.x;
    const int batch = w >> 6, wi = w & 63;
    const int wy = wi >> 3, wx = wi & 7;
    const f32x4 zero4 = {0.f, 0.f, 0.f, 0.f};

    for (int rr = 0; rr < 16; ++rr) {
        int row = wave * 16 + rr;
        if (row < 49) {
            int ty = row / 7, tx = row % 7;
            int y  = wy * 7 + ty + 3; if (y >= 56) y -= 56;
            int xx = wx * 7 + tx + 3; if (xx >= 56) xx -= 56;
            const float* xr = x + (size_t)(batch * 3136 + y * 56 + xx) * CC;
            float v0 = xr[lane], v1 = xr[lane + 64], v2 = xr[lane + 128];
            float s = v0 + v1 + v2;
            #pragma unroll
            for (int m = 32; m; m >>= 1) s += __shfl_xor(s, m);
            float mu = s * (1.0f / 192.0f);
            float d0 = v0 - mu, d1 = v1 - mu, d2 = v2 - mu;
            float q = d0 * d0 + d1 * d1 + d2 * d2;
            #pragma unroll
            for (int m = 32; m; m >>= 1) q += __shfl_xor(q, m);
            float rs = rsqrtf(q * (1.0f / 192.0f) + 1e-5f);
            xln[row * 200 + lane]       = f2bf(d0 * rs * n1g[lane]       + n1b[lane]);
            xln[row * 200 + lane + 64]  = f2bf(d1 * rs * n1g[lane + 64]  + n1b[lane + 64]);
            xln[row * 200 + lane + 128] = f2bf(d2 * rs * n1g[lane + 128] + n1b[lane + 128]);
        } else {
            xln[row * 200 + lane] = 0; xln[row * 200 + lane + 64] = 0; xln[row * 200 + lane + 128] = 0;
        }
    }

    f32x4 accP[12];
    #pragma unroll
    for (int n = 0; n < 12; ++n) accP[n] = zero4;
    const float scale = 0.17677669529663689f;
    const float* mptr = maskT + wi * 2401;

    for (int h = 0; h < 6; ++h) {
        f32x4 acc6[6];
        #pragma unroll
        for (int n = 0; n < 6; ++n) acc6[n] = zero4;
        const int cb0 = h * 32;
        for (int kk = 0; kk < 6; ++kk) {
            short8 a = *(const short8*)(xln + (wave * 16 + ln16) * 200 + kk * 32 + 8 * sub);
            #pragma unroll
            for (int n = 0; n < 6; ++n) {
                int colbase = (n >> 1) * 192 + cb0 + (n & 1) * 16;
                short8 b = *(const short8*)(qkvT + (size_t)(colbase + ln16) * 192 + kk * 32 + 8 * sub);
                acc6[n] = mfma16(a, b, acc6[n]);
            }
        }
        #pragma unroll
        for (int n = 0; n < 6; ++n) {
            int colbase = (n >> 1) * 192 + cb0 + (n & 1) * 16;
            float bv = qkv_b[colbase + ln16];
            int dim = (n & 1) * 16 + ln16;
            #pragma unroll
            for (int r = 0; r < 4; ++r) {
                int row = wave * 16 + 4 * sub + r;
                ushort_t hv = f2bf(acc6[n][r] + bv);
                if (n < 2)      qo[row * 40 + dim] = hv;
                else if (n < 4) kl[row * 40 + dim] = hv;
                else            vt[dim * 72 + row] = hv;
            }
        }
        __syncthreads();

        f32x4 s4[4];
        {
            short8 aq = *(const short8*)(qo + (wave * 16 + ln16) * 40 + 8 * sub);
            #pragma unroll
            for (int n = 0; n < 4; ++n) {
                short8 bk = *(const short8*)(kl + (n * 16 + ln16) * 40 + 8 * sub);
                s4[n] = mfma16(aq, bk, zero4);
            }
        }
        const float* bptr = biasT + h * 2401;
        #pragma unroll
        for (int n = 0; n < 4; ++n) {
            int col = n * 16 + ln16;
            #pragma unroll
            for (int r = 0; r < 4; ++r) {
                int row = wave * 16 + 4 * sub + r;
                s4[n][r] = (row < 49 && col < 49)
                    ? s4[n][r] * scale + bptr[row * 49 + col] + mptr[row * 49 + col]
                    : -1e30f;
            }
        }
        #pragma unroll
        for (int r = 0; r < 4; ++r) {
            float mx = fmaxf(fmaxf(s4[0][r], s4[1][r]), fmaxf(s4[2][r], s4[3][r]));
            mx = fmaxf(mx, __shfl_xor(mx, 1, 16));
            mx = fmaxf(mx, __shfl_xor(mx, 2, 16));
            mx = fmaxf(mx, __shfl_xor(mx, 4, 16));
            mx = fmaxf(mx, __shfl_xor(mx, 8, 16));
            float e0 = __expf(s4[0][r] - mx), e1 = __expf(s4[1][r] - mx);
            float e2 = __expf(s4[2][r] - mx), e3 = __expf(s4[3][r] - mx);
            float sm = e0 + e1 + e2 + e3;
            sm += __shfl_xor(sm, 1, 16);
            sm += __shfl_xor(sm, 2, 16);
            sm += __shfl_xor(sm, 4, 16);
            sm += __shfl_xor(sm, 8, 16);
            float inv = 1.0f / sm;
            int row = wave * 16 + 4 * sub + r;
            Pl[row * 72 +      ln16] = f2bf(e0 * inv);
            Pl[row * 72 + 16 + ln16] = f2bf(e1 * inv);
            Pl[row * 72 + 32 + ln16] = f2bf(e2 * inv);
            Pl[row * 72 + 48 + ln16] = f2bf(e3 * inv);
        }
        f32x4 o2[2]; o2[0] = zero4; o2[1] = zero4;
        #pragma unroll
        for (int ks = 0; ks < 2; ++ks) {
            short8 ap = *(const short8*)(Pl + (wave * 16 + ln16) * 72 + ks * 32 + 8 * sub);
            #pragma unroll
            for (int n2 = 0; n2 < 2; ++n2) {
                short8 bv = *(const short8*)(vt + (n2 * 16 + ln16) * 72 + ks * 32 + 8 * sub);
                o2[n2] = mfma16(ap, bv, o2[n2]);
            }
        }
        #pragma unroll
        for (int n2 = 0; n2 < 2; ++n2)
            #pragma unroll
            for (int r = 0; r < 4; ++r) {
                int row = wave * 16 + 4 * sub + r;
                qo[row * 40 + n2 * 16 + ln16] = f2bf(o2[n2][r]);
            }
        {
            short8 ao = *(const short8*)(qo + (wave * 16 + ln16) * 40 + 8 * sub);
            #pragma unroll
            for (int n = 0; n < 12; ++n) {
                short8 bp = *(const short8*)(projT + (size_t)(n * 16 + ln16) * 192 + h * 32 + 8 * sub);
                accP[n] = mfma16(ao, bp, accP[n]);
            }
        }
        __syncthreads();
    }

    #pragma unroll
    for (int n = 0; n < 12; ++n) {
        int col = n * 16 + ln16;
        float pb = proj_b[col];
        #pragma unroll
        for (int r = 0; r < 4; ++r) {
            int row = wave * 16 + 4 * sub + r;
            if (row < 49) {
                int ty = row / 7, tx = row % 7;
                int y  = wy * 7 + ty + 3; if (y >= 56) y -= 56;
                int xx = wx * 7 + tx + 3; if (xx >= 56) xx -= 56;
                size_t g = (size_t)(batch * 3136 + y * 56 + xx) * CC;
                out[g + col] = accP[n][r] + pb + x[g + col];
            }
        }
    }
}

// ---------------- fallback MLP (round-7 mlp5) ----------------
__global__ __launch_bounds__(256, 3) void mlp5_kernel(
    float* __restrict__ out, const float* __restrict__ n2g, const float* __restrict__ n2b,
    const float* __restrict__ fc1_b, const float* __restrict__ fc2_b,
    const ushort_t* __restrict__ fc1T, const ushort_t* __restrict__ fc2T) {
    __shared__ ushort_t smem[2][64 * 200];
    ushort_t* aln  = smem[0];
    ushort_t* hidc = smem[1];
    float* fout = (float*)&smem[0][0];
    const int tid = threadIdx.x;
    const int wave = tid >> 6, lane = tid & 63;
    const int ln16 = lane & 15, sub = lane >> 4;
    const size_t t0 = (size_t)blockIdx.x * 64;
    const f32x4 zero4 = {0.f, 0.f, 0.f, 0.f};

    short8 b1p[3];
    #pragma unroll
    for (int n = 0; n < 3; ++n)
        b1p[n] = *(const short8*)(fc1T + (size_t)(wave * 48 + n * 16 + ln16) * 192 + 8 * sub);

    {
        float g0 = n2g[lane], g1 = n2g[lane + 64], g2 = n2g[lane + 128];
        float bb0 = n2b[lane], bb1 = n2b[lane + 64], bb2 = n2b[lane + 128];
        for (int rb = 0; rb < 4; ++rb) {
            int row0 = wave * 16 + rb * 4;
            float v0[4], v1[4], v2[4], s[4], q[4];
            #pragma unroll
            for (int j = 0; j < 4; ++j) {
                const float* xr = out + (t0 + row0 + j) * CC;
                v0[j] = xr[lane]; v1[j] = xr[lane + 64]; v2[j] = xr[lane + 128];
            }
            #pragma unroll
            for (int j = 0; j < 4; ++j) {
                s[j] = v0[j] + v1[j] + v2[j];
                q[j] = v0[j] * v0[j] + v1[j] * v1[j] + v2[j] * v2[j];
            }
            #pragma unroll
            for (int m = 32; m; m >>= 1) {
                #pragma unroll
                for (int j = 0; j < 4; ++j) { s[j] += __shfl_xor(s[j], m); q[j] += __shfl_xor(q[j], m); }
            }
            #pragma unroll
            for (int j = 0; j < 4; ++j) {
                float mu = s[j] * (1.0f / 192.0f);
                float var = q[j] * (1.0f / 192.0f) - mu * mu;
                float rs = rsqrtf(var + 1e-5f);
                int row = row0 + j;
                aln[row * 200 + lane]       = f2bf((v0[j] - mu) * rs * g0 + bb0);
                aln[row * 200 + lane + 64]  = f2bf((v1[j] - mu) * rs * g1 + bb1);
                aln[row * 200 + lane + 128] = f2bf((v2[j] - mu) * rs * g2 + bb2);
            }
        }
    }
    __syncthreads();

    f32x4 accO[4][3];
    #pragma unroll
    for (int m = 0; m < 4; ++m)
        #pragma unroll
        for (int n = 0; n < 3; ++n) accO[m][n] = zero4;

    for (int c = 0; c < 4; ++c) {
        f32x4 acc1[4][3];
        #pragma unroll
        for (int m = 0; m < 4; ++m)
            #pragma unroll
            for (int n = 0; n < 3; ++n) acc1[m][n] = zero4;
        #pragma unroll
        for (int kk = 0; kk < 6; ++kk) {
            short8 a[4];
            #pragma unroll
            for (int m = 0; m < 4; ++m)
                a[m] = *(const short8*)(aln + (m * 16 + ln16) * 200 + kk * 32 + 8 * sub);
            short8 bb[3];
            if (kk == 0) {
                bb[0] = b1p[0]; bb[1] = b1p[1]; bb[2] = b1p[2];
            } else {
                #pragma unroll
                for (int n = 0; n < 3; ++n)
                    bb[n] = *(const short8*)(fc1T + (size_t)(c * 192 + wave * 48 + n * 16 + ln16) * 192 + kk * 32 + 8 * sub);
            }
            #pragma unroll
            for (int n = 0; n < 3; ++n)
                #pragma unroll
                for (int m = 0; m < 4; ++m) acc1[m][n] = mfma16(a[m], bb[n], acc1[m][n]);
        }
        short8 b2p[3];
        #pragma unroll
        for (int n = 0; n < 3; ++n)
            b2p[n] = *(const short8*)(fc2T + (size_t)(wave * 48 + n * 16 + ln16) * 768 + c * 192 + 8 * sub);
        if (c < 3) {
            #pragma unroll
            for (int n = 0; n < 3; ++n)
                b1p[n] = *(const short8*)(fc1T + (size_t)((c + 1) * 192 + wave * 48 + n * 16 + ln16) * 192 + 8 * sub);
        }
        #pragma unroll
        for (int n = 0; n < 3; ++n) {
            int cl = wave * 48 + n * 16 + ln16;
            float fb = fc1_b[c * 192 + cl];
            #pragma unroll
            for (int m = 0; m < 4; ++m)
                #pragma unroll
                for (int r = 0; r < 4; ++r) {
                    float hv = acc1[m][n][r] + fb;
                    hidc[(m * 16 + 4 * sub + r) * 200 + cl] = f2bf(fast_gelu(hv));
                }
        }
        __syncthreads();
        #pragma unroll
        for (int kk = 0; kk < 6; ++kk) {
            short8 a[4];
            #pragma unroll
            for (int m = 0; m < 4; ++m)
                a[m] = *(const short8*)(hidc + (m * 16 + ln16) * 200 + kk * 32 + 8 * sub);
            short8 bb[3];
            if (kk == 0) {
                bb[0] = b2p[0]; bb[1] = b2p[1]; bb[2] = b2p[2];
            } else {
                #pragma unroll
                for (int n = 0; n < 3; ++n)
                    bb[n] = *(const short8*)(fc2T + (size_t)(wave * 48 + n * 16 + ln16) * 768 + c * 192 + kk * 32 + 8 * sub);
            }
            #pragma unroll
            for (int n = 0; n < 3; ++n)
                #pragma unroll
                for (int m = 0; m < 4; ++m) accO[m][n] = mfma16(a[m], bb[n], accO[m][n]);
        }
        __syncthreads();
    }

    #pragma unroll
    for (int n = 0; n < 3; ++n) {
        int col = wave * 48 + n * 16 + ln16;
        float fb = fc2_b[col];
        #pragma unroll
        for (int m = 0; m < 4; ++m)
            #pragma unroll
            for (int r = 0; r < 4; ++r)
                fout[(m * 16 + 4 * sub + r) * 196 + col] = accO[m][n][r] + fb;
    }
    __syncthreads();
    for (int i = tid; i < 3072; i += 256) {
        int row = i / 48, c4 = (i % 48) * 4;
        f32x4 sv = *(const f32x4*)(fout + row * 196 + c4);
        float* op = out + (t0 + row) * CC + c4;
        f32x4 ov = *(const f32x4*)op;
        #pragma unroll
        for (int q = 0; q < 4; ++q) ov[q] += sv[q];
        *(f32x4*)op = ov;
    }
}

// ---------------- launch ----------------
extern "C" void kernel_launch(void* const* d_in, const int* in_sizes, int n_in,
                              void* d_out, int out_size, void* d_ws, size_t ws_size,
                              hipStream_t stream) {
    const float* x      = (const float*)d_in[0];
    const float* n1g    = (const float*)d_in[1];
    const float* n1b    = (const float*)d_in[2];
    const float* qkv_w  = (const float*)d_in[3];
    const float* qkv_b  = (const float*)d_in[4];
    const float* rel_t  = (const float*)d_in[5];
    const float* proj_w = (const float*)d_in[6];
    const float* proj_b = (const float*)d_in[7];
    const float* n2g    = (const float*)d_in[8];
    const float* n2b    = (const float*)d_in[9];
    const float* fc1_w  = (const float*)d_in[10];
    const float* fc1_b  = (const float*)d_in[11];
    const float* fc2_w  = (const float*)d_in[12];
    const float* fc2_b  = (const float*)d_in[13];
    float* out = (float*)d_out;

    char* ws = (char*)d_ws;
    ushort_t* qkvT  = (ushort_t*)(ws + OFF_QKVT);
    ushort_t* projT = (ushort_t*)(ws + OFF_PROJT);
    ushort_t* fc1T  = (ushort_t*)(ws + OFF_FC1T);
    ushort_t* fc2T  = (ushort_t*)(ws + OFF_FC2T);
    float* biasT    = (float*)(ws + OFF_BIAS);
    float* maskT    = (float*)(ws + OFF_MASK);
    float* bmT      = (float*)(ws + OFF_BMT);
    ushort_t* qg    = (ushort_t*)(ws + OFF_QG);
    ushort_t* kg    = (ushort_t*)(ws + OFF_KG);
    ushort_t* vg    = (ushort_t*)(ws + OFF_VG);

    const int big = ws_size >= (size_t)WS_NEED;
    const int prep_total = big ? PREP_BIG : PREP_SMALL;
    prep_kernel<<<(prep_total + 255) / 256, 256, 0, stream>>>(
        qkv_w, proj_w, fc1_w, fc2_w, rel_t, qkvT, projT, fc1T, fc2T, biasT, maskT, bmT, big);

    if (big) {
        lnqkv_kernel<<<1568, 256, 0, stream>>>(x, n1g, n1b, qkvT, qkv_b, qg, kg, vg);
        attnmlp_kernel<<<2048, 256, 0, stream>>>(x, proj_b, qg, kg, vg, projT, bmT,
                                                 n2g, n2b, fc1_b, fc2_b, fc1T, fc2T, out);
    } else {
        attn_kernel<<<2048, 256, 0, stream>>>(x, n1g, n1b, qkv_b, proj_b,
                                              qkvT, projT, biasT, maskT, out);
        mlp5_kernel<<<1568, 256, 0, stream>>>(out, n2g, n2b, fc1_b, fc2_b, fc1T, fc2T);
    }
}